// Round 9
// baseline (130.066 us; speedup 1.0000x reference)
//
#include <hip/hip_runtime.h>

#define NB    256   // neighbors
#define DIN   64
#define LATD  128
#define ECD   32

typedef __attribute__((ext_vector_type(8))) __bf16 bf16x8;
typedef __attribute__((ext_vector_type(4))) float f32x4;

#define XS_STRIDE 72   // row stride for WcT/WfT (bf16 elems)
#define EC_STRIDE 40   // 32 data + 8 pad (LDS bank spread)
#define WA_STRIDE 40

// d_ws layout (unsigned short elements)
#define WS_WC 0                     // WcT  [32][72]
#define WS_WF (32 * 72)             // WfT  [128][72]
#define WS_WA (32 * 72 + 128 * 72)  // WaTm [128][40]  (Wa rows 32..63, transposed, *log2e)
// WfT and WaTm are contiguous: one 14336-short (28672 B) staging chunk.
#define WSTAGE_SHORTS (128 * 72 + 128 * 40)
#define WA_OFF (128 * 72)           // offset of WaTm inside the staged chunk

#define MFMA(a, b, c) __builtin_amdgcn_mfma_f32_16x16x32_bf16((a), (b), (c), 0, 0, 0)

__device__ __forceinline__ unsigned short f2bf(float f) {
    unsigned u = __builtin_bit_cast(unsigned, f);
    u += 0x7fffu + ((u >> 16) & 1u);   // round-to-nearest-even
    return (unsigned short)(u >> 16);
}

// Packed f32->bf16 RNE: 1 instruction per 2 elements (gfx950; no builtin).
// Plain VALU op -> no TRANS hazard, safe as opaque asm (verified r2..r8).
__device__ __forceinline__ unsigned cvt2(float lo, float hi) {
    unsigned r;
    asm("v_cvt_pk_bf16_f32 %0, %1, %2" : "=v"(r) : "v"(lo), "v"(hi));
    return r;
}

// Single-instruction exp2. r4 LESSON: raw `asm("v_exp_f32")` FAILS —
// TRANS-op results need a wait state before a dependent VALU read and the
// compiler's hazard recognizer can't see through opaque asm (absmax 1.5).
// The builtin emits v_exp_f32 with compiler-managed hazards (r5 verified).
#if __has_builtin(__builtin_amdgcn_exp2f)
__device__ __forceinline__ float fexp2(float x) {
    return __builtin_amdgcn_exp2f(x);
}
#else
__device__ __forceinline__ float fexp2(float x) {
    float r;
    asm("v_exp_f32 %0, %1\n\ts_nop 1" : "=v"(r) : "v"(x));
    return r;
}
#endif

__device__ __forceinline__ bf16x8 pack8(float4 a, float4 b) {
    union { unsigned u[4]; bf16x8 v; } r;
    r.u[0] = cvt2(a.x, a.y);
    r.u[1] = cvt2(a.z, a.w);
    r.u[2] = cvt2(b.x, b.y);
    r.u[3] = cvt2(b.z, b.w);
    return r.v;
}

// Pre-transpose weights into bf16 B-fragment-friendly [n][k] layouts in d_ws.
// Wa rows 32..63 are pre-scaled by log2e so the kernel can use exp2 directly.
__global__ __launch_bounds__(256) void prep_kernel(
    const float* __restrict__ Wc, const float* __restrict__ Wf,
    const float* __restrict__ Wa, unsigned short* __restrict__ ws)
{
    int t = blockIdx.x * blockDim.x + threadIdx.x;
    int stride = gridDim.x * blockDim.x;
    for (int i = t; i < 32 * 64; i += stride) {
        int n = i >> 6, k = i & 63;
        ws[WS_WC + n * XS_STRIDE + k] = f2bf(Wc[k * ECD + n]);
    }
    for (int i = t; i < 128 * 64; i += stride) {
        int n = i >> 6, k = i & 63;
        ws[WS_WF + n * XS_STRIDE + k] = f2bf(Wf[k * LATD + n]);
    }
    for (int i = t; i < 128 * 32; i += stride) {
        int n = i >> 5, k = i & 31;
        ws[WS_WA + n * WA_STRIDE + k] = f2bf(Wa[(ECD + k) * LATD + n] * 1.44269504f);
    }
}

// FOUR batch elements per block, interleaved, 256 blocks = 1 block/CU =
// 1 wave/SIMD. r2..r8 ladder fits duration ~= (waves/SIMD) x (per-wave
// chain): symmetric waves stall in lockstep (all pipes <21% busy), TLP
// never engages, so only within-wave ILP moves time (r7: 2-elem interleave
// cut per-element chain 33 -> 21-23 us). This rev maximizes that lever:
// 4 independent chains per wave, duration = chain(4elem) directly.
// __launch_bounds__(256,1) -> up to 512 VGPR (est. peak ~300, no spill
// through ~450 per m08). LDS via a 51.7 KB arena: ecs is dead before any
// agg write (ecs accesses are wave-private, all precede the staging
// barrier; agg writes all follow it) -> agg region overlays ecs.
// Key algebra (verified): self_rep/mean_rep/ba constant along n -> cancel
// in softmax(axis=n); att = softmax_n(enc_comm @ Wa[32:64]); local_data /
// Wa[0:32] / Wa[64:96] / ba never touch the output.
__global__ __launch_bounds__(256, 1) void arm_main(
    const float* __restrict__ xg,   // neighbor [B][256][64]
    const float* __restrict__ bcv,  // bc [32]
    const float* __restrict__ bfv,  // bf [128]
    const float* __restrict__ wl,   // Wl [128][128]
    const float* __restrict__ blv,  // bl [128]
    const unsigned short* __restrict__ ws,
    float* __restrict__ out)        // [B][128]
{
    // ---- shared arena, 51712 B ----
    // [0,28672)           wstage: WfT+WaTm bf16
    // [28672,49152)       ecs [256][EC_STRIDE] bf16   (dead after enc)
    //   overlay:
    // [28672,36864)       aggnum [4e][4w][128] f32
    // [36864,45056)       aggden [4e][4w][128] f32
    // [45056,47104)       aggfull [4e][128] f32
    // [47104,51200)       wlpart [2h][4e][128] f32
    // [51200,51712)       bfs [128] f32
    __shared__ __align__(16) unsigned char arena[51712];
    unsigned short* wstage = reinterpret_cast<unsigned short*>(arena);
    unsigned short* ecs    = reinterpret_cast<unsigned short*>(arena + 28672);
    float* aggnum  = reinterpret_cast<float*>(arena + 28672);
    float* aggden  = reinterpret_cast<float*>(arena + 28672 + 8192);
    float* aggfull = reinterpret_cast<float*>(arena + 28672 + 16384);
    float* wlpartm = reinterpret_cast<float*>(arena + 28672 + 18432);
    float* bfs     = reinterpret_cast<float*>(arena + 28672 + 22528);

    const int tid  = threadIdx.x;
    const int lane = tid & 63;
    const int w    = tid >> 6;   // wave id, owns rows 64w..64w+63 (4 m-tiles)
    const int l15  = lane & 15;
    const int q    = lane >> 4;

    // ---- issue weight-staging loads (L2, small) FIRST (in-order vmem
    // queue -> they complete before the X loads; staging ds_writes below
    // don't wait on X). 1792 uint4 chunks = exactly 7 per thread.
    uint4 wch[7];
    {
        const uint4* src = reinterpret_cast<const uint4*>(ws + WS_WF);
        #pragma unroll
        for (int i = 0; i < 7; ++i)
            wch[i] = src[tid + i * 256];
    }
    uint4 bfch;
    if (tid < 32) bfch = reinterpret_cast<const uint4*>(bfv)[tid];

    // ---- element-invariant front-loads: Wc frags + bc (L2) ----
    bf16x8 wfrag[2][2];   // [khalf][colblock]
    #pragma unroll
    for (int ks = 0; ks < 2; ++ks)
        #pragma unroll
        for (int nb = 0; nb < 2; ++nb)
            wfrag[ks][nb] = *reinterpret_cast<const bf16x8*>(
                &ws[WS_WC + (nb * 16 + l15) * XS_STRIDE + ks * 32 + q * 8]);
    float bc0 = bcv[l15], bc1 = bcv[16 + l15];

    // ---- X load / pack / enc_comm pipeline over 4 elements ----
    // A-frag: row = lane&15 (within tile), k = quad*8 + j -> 8 contiguous
    // floats. Two st register sets double-buffer the HBM loads.
    const int xrow = (w * 64 + l15) * DIN + q * 8;   // t advances +16*DIN
    float4 stA[4][4], stB[4][4];
    bf16x8 xfrag[4][4][2];   // [elem][tile][khalf]
    bf16x8 ecfrag[4][4];     // [elem][tile]

#define XLOAD(dst, bidx)                                                      \
    {                                                                         \
        const float* xb = xg + (size_t)(bidx) * NB * DIN + xrow;              \
        _Pragma("unroll")                                                     \
        for (int t = 0; t < 4; ++t) {                                         \
            const float* p = xb + t * 16 * DIN;                               \
            dst[t][0] = *reinterpret_cast<const float4*>(p);                  \
            dst[t][1] = *reinterpret_cast<const float4*>(p + 4);              \
            dst[t][2] = *reinterpret_cast<const float4*>(p + 32);             \
            dst[t][3] = *reinterpret_cast<const float4*>(p + 36);             \
        }                                                                     \
    }

#define PACK_ENC(e, src)                                                      \
    {                                                                         \
        _Pragma("unroll")                                                     \
        for (int t = 0; t < 4; ++t) {                                         \
            xfrag[e][t][0] = pack8(src[t][0], src[t][1]);                     \
            xfrag[e][t][1] = pack8(src[t][2], src[t][3]);                     \
        }                                                                     \
        _Pragma("unroll")                                                     \
        for (int t = 0; t < 4; ++t) {                                         \
            int rowA = w * 64 + t * 16;                                       \
            f32x4 a0 = {bc0, bc0, bc0, bc0};  /* bias in acc init */          \
            f32x4 a1 = {bc1, bc1, bc1, bc1};                                  \
            _Pragma("unroll")                                                 \
            for (int ks = 0; ks < 2; ++ks) {                                  \
                a0 = MFMA(xfrag[e][t][ks], wfrag[ks][0], a0);                 \
                a1 = MFMA(xfrag[e][t][ks], wfrag[ks][1], a1);                 \
            }                                                                 \
            _Pragma("unroll")                                                 \
            for (int r = 0; r < 4; ++r) {                                     \
                int row = rowA + q * 4 + r;  /* C/D: row = quad*4 + reg */    \
                unsigned pk = cvt2(fmaxf(a0[r], 0.f), fmaxf(a1[r], 0.f));     \
                ecs[row * EC_STRIDE + l15]      = (unsigned short)pk;         \
                ecs[row * EC_STRIDE + 16 + l15] = (unsigned short)(pk >> 16); \
            }                                                                 \
        }                                                                     \
        _Pragma("unroll")                                                     \
        for (int t = 0; t < 4; ++t)                                           \
            ecfrag[e][t] = *reinterpret_cast<const bf16x8*>(                  \
                &ecs[(w * 64 + t * 16 + l15) * EC_STRIDE + q * 8]);           \
    }

    const int b0 = blockIdx.x;         // gridDim.x == 256; elems b0+256*e
    XLOAD(stA, b0);
    XLOAD(stB, b0 + 256);

    // ---- write staged weights to LDS (waits only on the staging loads) ----
    {
        uint4* dst = reinterpret_cast<uint4*>(wstage);
        #pragma unroll
        for (int i = 0; i < 7; ++i)
            dst[tid + i * 256] = wch[i];
        if (tid < 32) reinterpret_cast<uint4*>(bfs)[tid] = bfch;
    }

    PACK_ENC(0, stA);
    XLOAD(stA, b0 + 512);
    PACK_ENC(1, stB);
    XLOAD(stB, b0 + 768);
    PACK_ENC(2, stA);
    PACK_ENC(3, stB);

    // staging + overlay barrier: all wstage/bfs writes visible, and all
    // (wave-private) ecs use finished before the agg overlay is written.
    __syncthreads();

    // ---- fused g-loop, 4 elements interleaved: enc_feature + logits +
    // unnormalized softmax agg. Zero VMEM in the loop (weights via
    // ds_read_b128). No max-subtraction (logits O(+-3); exp2 safe). The
    // 4 chains are independent -> MFMA/exp/shuffle latencies overlap.
    for (int g = 0; g < 8; ++g) {
        const int r0 = g * 16 + l15;
        bf16x8 wf0 = *reinterpret_cast<const bf16x8*>(&wstage[r0 * XS_STRIDE + q * 8]);
        bf16x8 wf1 = *reinterpret_cast<const bf16x8*>(&wstage[r0 * XS_STRIDE + 32 + q * 8]);
        bf16x8 wag = *reinterpret_cast<const bf16x8*>(&wstage[WA_OFF + r0 * WA_STRIDE + q * 8]);
        float  bfl = bfs[r0];

        float num[4] = {0.f, 0.f, 0.f, 0.f};
        float den[4] = {0.f, 0.f, 0.f, 0.f};
        #pragma unroll
        for (int t = 0; t < 4; ++t) {
            #pragma unroll
            for (int e = 0; e < 4; ++e) {
                f32x4 z = {bfl, bfl, bfl, bfl};   // bf bias in acc init
                z = MFMA(xfrag[e][t][0], wf0, z);
                f32x4 ef = MFMA(xfrag[e][t][1], wf1, z);
                f32x4 zz = {0.f, 0.f, 0.f, 0.f};  // ba cancels
                f32x4 lg = MFMA(ecfrag[e][t], wag, zz);
                #pragma unroll
                for (int r = 0; r < 4; ++r) {
                    float ev = fmaxf(ef[r], 0.f);
                    float p  = fexp2(lg[r]);   // Wa pre-scaled by log2e
                    num[e] = fmaf(p, ev, num[e]);
                    den[e] += p;
                }
            }
        }
        #pragma unroll
        for (int e = 0; e < 4; ++e) {
            num[e] += __shfl_xor(num[e], 16, 64);
            num[e] += __shfl_xor(num[e], 32, 64);
            den[e] += __shfl_xor(den[e], 16, 64);
            den[e] += __shfl_xor(den[e], 32, 64);
        }
        if (lane < 16) {
            #pragma unroll
            for (int e = 0; e < 4; ++e) {
                aggnum[(e * 4 + w) * LATD + g * 16 + lane] = num[e];
                aggden[(e * 4 + w) * LATD + g * 16 + lane] = den[e];
            }
        }
    }
    __syncthreads();

    // ---- combine wave partials: each thread covers 2 elements ----
    {
        int c = tid & 127, eh = tid >> 7;
        #pragma unroll
        for (int e0 = 0; e0 < 2; ++e0) {
            int e = eh + e0 * 2;
            float num = aggnum[(e * 4 + 0) * LATD + c] + aggnum[(e * 4 + 1) * LATD + c]
                      + aggnum[(e * 4 + 2) * LATD + c] + aggnum[(e * 4 + 3) * LATD + c];
            float den = aggden[(e * 4 + 0) * LATD + c] + aggden[(e * 4 + 1) * LATD + c]
                      + aggden[(e * 4 + 2) * LATD + c] + aggden[(e * 4 + 3) * LATD + c];
            aggfull[e * LATD + c] = num / den;
        }
    }
    __syncthreads();

    // ---- out = relu(agg @ Wl + bl): wl loaded ONCE for all 4 elements ----
    {
        int c = tid & 127, h = tid >> 7;
        float acc[4] = {0.f, 0.f, 0.f, 0.f};
        #pragma unroll 16
        for (int k = h * 64; k < h * 64 + 64; ++k) {
            float wv = wl[k * LATD + c];
            #pragma unroll
            for (int e = 0; e < 4; ++e)
                acc[e] = fmaf(aggfull[e * LATD + k], wv, acc[e]);
        }
        #pragma unroll
        for (int e = 0; e < 4; ++e)
            wlpartm[(h * 4 + e) * LATD + c] = acc[e];
    }
    __syncthreads();
    {
        int c = tid & 127, eh = tid >> 7;
        #pragma unroll
        for (int e0 = 0; e0 < 2; ++e0) {
            int e = eh + e0 * 2;
            out[(size_t)(b0 + e * 256) * LATD + c] =
                fmaxf(wlpartm[(0 * 4 + e) * LATD + c] +
                      wlpartm[(1 * 4 + e) * LATD + c] + blv[c], 0.f);
        }
    }
#undef XLOAD
#undef PACK_ENC
}

extern "C" void kernel_launch(void* const* d_in, const int* in_sizes, int n_in,
                              void* d_out, int out_size, void* d_ws, size_t ws_size,
                              hipStream_t stream)
{
    const float* xg  = (const float*)d_in[1];
    const float* wc  = (const float*)d_in[2];
    const float* bc_ = (const float*)d_in[3];
    const float* wf  = (const float*)d_in[4];
    const float* bf_ = (const float*)d_in[5];
    const float* wa  = (const float*)d_in[6];
    const float* wl  = (const float*)d_in[8];
    const float* bl_ = (const float*)d_in[9];
    unsigned short* wsp = (unsigned short*)d_ws;   // needs 33,280 B of ws
    float* out = (float*)d_out;

    prep_kernel<<<8, 256, 0, stream>>>(wc, wf, wa, wsp);
    arm_main<<<256, 256, 0, stream>>>(xg, bc_, bf_, wl, bl_, wsp, out);
}

// Round 10
// 125.859 us; speedup vs baseline: 1.0334x; 1.0334x over previous
//
#include <hip/hip_runtime.h>

#define NB    256   // neighbors
#define DIN   64
#define LATD  128
#define ECD   32

typedef __attribute__((ext_vector_type(8))) __bf16 bf16x8;
typedef __attribute__((ext_vector_type(4))) float f32x4;

#define XS_STRIDE 72   // row stride for WcT/WfT (bf16 elems)
#define EC_STRIDE 40   // 32 data + 8 pad (LDS bank spread)
#define WA_STRIDE 40

// d_ws layout (unsigned short elements)
#define WS_WC 0                     // WcT  [32][72]
#define WS_WF (32 * 72)             // WfT  [128][72]
#define WS_WA (32 * 72 + 128 * 72)  // WaTm [128][40]  (Wa rows 32..63, transposed, *log2e)

#define MFMA(a, b, c) __builtin_amdgcn_mfma_f32_16x16x32_bf16((a), (b), (c), 0, 0, 0)

__device__ __forceinline__ unsigned short f2bf(float f) {
    unsigned u = __builtin_bit_cast(unsigned, f);
    u += 0x7fffu + ((u >> 16) & 1u);   // round-to-nearest-even
    return (unsigned short)(u >> 16);
}

// Packed f32->bf16 RNE: 1 instruction per 2 elements (gfx950; no builtin).
// Plain VALU op -> no TRANS hazard, safe as opaque asm (verified r2..r9).
__device__ __forceinline__ unsigned cvt2(float lo, float hi) {
    unsigned r;
    asm("v_cvt_pk_bf16_f32 %0, %1, %2" : "=v"(r) : "v"(lo), "v"(hi));
    return r;
}

// Single-instruction exp2. r4 LESSON: raw `asm("v_exp_f32")` FAILS —
// TRANS-op results need a wait state before a dependent VALU read and the
// compiler's hazard recognizer can't see through opaque asm (absmax 1.5).
// The builtin emits v_exp_f32 with compiler-managed hazards (r5 verified).
#if __has_builtin(__builtin_amdgcn_exp2f)
__device__ __forceinline__ float fexp2(float x) {
    return __builtin_amdgcn_exp2f(x);
}
#else
__device__ __forceinline__ float fexp2(float x) {
    float r;
    asm("v_exp_f32 %0, %1\n\ts_nop 1" : "=v"(r) : "v"(x));
    return r;
}
#endif

__device__ __forceinline__ bf16x8 pack8(float4 a, float4 b) {
    union { unsigned u[4]; bf16x8 v; } r;
    r.u[0] = cvt2(a.x, a.y);
    r.u[1] = cvt2(a.z, a.w);
    r.u[2] = cvt2(b.x, b.y);
    r.u[3] = cvt2(b.z, b.w);
    return r.v;
}

// Pre-transpose weights into bf16 B-fragment-friendly [n][k] layouts in d_ws.
// Wa rows 32..63 are pre-scaled by log2e so the kernel can use exp2 directly.
__global__ __launch_bounds__(256) void prep_kernel(
    const float* __restrict__ Wc, const float* __restrict__ Wf,
    const float* __restrict__ Wa, unsigned short* __restrict__ ws)
{
    int t = blockIdx.x * blockDim.x + threadIdx.x;
    int stride = gridDim.x * blockDim.x;
    for (int i = t; i < 32 * 64; i += stride) {
        int n = i >> 6, k = i & 63;
        ws[WS_WC + n * XS_STRIDE + k] = f2bf(Wc[k * ECD + n]);
    }
    for (int i = t; i < 128 * 64; i += stride) {
        int n = i >> 6, k = i & 63;
        ws[WS_WF + n * XS_STRIDE + k] = f2bf(Wf[k * LATD + n]);
    }
    for (int i = t; i < 128 * 32; i += stride) {
        int n = i >> 5, k = i & 31;
        ws[WS_WA + n * WA_STRIDE + k] = f2bf(Wa[(ECD + k) * LATD + n] * 1.44269504f);
    }
}

// r9 post-mortem: 4-elem/1-wave-per-SIMD regressed (register pressure
// serialized the interleave; no co-resident blocks for phase overlap) ->
// REVERT to r8's proven optimum: 2 elems interleaved, 512 blocks,
// 2 blocks/CU. THIS REV's single change: all per-g weights (24 bf16x8
// frags + 8 bf scalars) hoisted into REGISTERS before the g-loop, loaded
// from d_ws global after the enc phase. The g-loop becomes zero-load pure
// register math — kills the loop-carried lgkmcnt exposure (3 ds_read_b128
// at every g head) that LDS staging (r8) still had. g-loop fully unrolled
// so frag arrays stay compile-time-indexed (runtime-indexed ext_vector
// arrays go to scratch). Steady VGPR est ~234 < 256 cap.
// Key algebra (verified): self_rep/mean_rep/ba constant along n -> cancel
// in softmax(axis=n); att = softmax_n(enc_comm @ Wa[32:64]); local_data /
// Wa[0:32] / Wa[64:96] / ba never touch the output.
__global__ __launch_bounds__(256, 2) void arm_main(
    const float* __restrict__ xg,   // neighbor [B][256][64]
    const float* __restrict__ bcv,  // bc [32]
    const float* __restrict__ bfv,  // bf [128]
    const float* __restrict__ wl,   // Wl [128][128]
    const float* __restrict__ blv,  // bl [128]
    const unsigned short* __restrict__ ws,
    float* __restrict__ out)        // [B][128]
{
    __shared__ unsigned short ecs[NB * EC_STRIDE];  // 20480 B, bf16 enc_comm
    __shared__ float aggnum[2][4][LATD];            // [elem][wave][col]
    __shared__ float aggden[2][4][LATD];
    __shared__ float aggfull[2][LATD];
    __shared__ float wlpart[2][2][LATD];            // [khalf][elem][col]
    // total 31744 B; 2 blocks/CU

    const int b0   = blockIdx.x;          // gridDim.x == 512
    const int b1   = blockIdx.x + 512;
    const int tid  = threadIdx.x;
    const int lane = tid & 63;
    const int w    = tid >> 6;   // wave id, owns rows 64w..64w+63 (4 m-tiles)
    const int l15  = lane & 15;
    const int q    = lane >> 4;

    // ---- element-invariant front-loads: Wc frags + bc (L2) ----
    bf16x8 wfrag[2][2];   // [khalf][colblock]
    #pragma unroll
    for (int ks = 0; ks < 2; ++ks)
        #pragma unroll
        for (int nb = 0; nb < 2; ++nb)
            wfrag[ks][nb] = *reinterpret_cast<const bf16x8*>(
                &ws[WS_WC + (nb * 16 + l15) * XS_STRIDE + ks * 32 + q * 8]);
    float bc0 = bcv[l15], bc1 = bcv[16 + l15];

    // ---- issue X loads for BOTH elements (32 dwordx4 in flight) ----
    // A-frag: row = lane&15 (within tile), k = quad*8 + j -> 8 contiguous floats.
    float4 st0[4][4], st1[4][4];
    {
        const float* xa = xg + (size_t)b0 * NB * DIN;
        const float* xc = xg + (size_t)b1 * NB * DIN;
        #pragma unroll
        for (int t = 0; t < 4; ++t) {
            const float* p = xa + (w * 64 + t * 16 + l15) * DIN + q * 8;
            st0[t][0] = *reinterpret_cast<const float4*>(p);
            st0[t][1] = *reinterpret_cast<const float4*>(p + 4);
            st0[t][2] = *reinterpret_cast<const float4*>(p + 32);
            st0[t][3] = *reinterpret_cast<const float4*>(p + 36);
        }
        #pragma unroll
        for (int t = 0; t < 4; ++t) {
            const float* p = xc + (w * 64 + t * 16 + l15) * DIN + q * 8;
            st1[t][0] = *reinterpret_cast<const float4*>(p);
            st1[t][1] = *reinterpret_cast<const float4*>(p + 4);
            st1[t][2] = *reinterpret_cast<const float4*>(p + 32);
            st1[t][3] = *reinterpret_cast<const float4*>(p + 36);
        }
    }

    // ---- pack both elements into A-fragments (st regs die here) ----
    bf16x8 xfrag[2][4][2];
    #pragma unroll
    for (int t = 0; t < 4; ++t) {
        xfrag[0][t][0] = pack8(st0[t][0], st0[t][1]);
        xfrag[0][t][1] = pack8(st0[t][2], st0[t][3]);
    }
    #pragma unroll
    for (int t = 0; t < 4; ++t) {
        xfrag[1][t][0] = pack8(st1[t][0], st1[t][1]);
        xfrag[1][t][1] = pack8(st1[t][2], st1[t][3]);
    }

    // ---- enc_comm per element -> ecs -> ecfrag (same-wave rows; same-wave
    // DS ops execute in order, so no barrier needed) ----
    bf16x8 ecfrag[2][4];
    #pragma unroll
    for (int e = 0; e < 2; ++e) {
        #pragma unroll
        for (int t = 0; t < 4; ++t) {
            int rowA = w * 64 + t * 16;
            // bias folded into accumulator init (C/D col = lane&15 -> bias
            // uniform across the 4 result regs).
            f32x4 a0 = {bc0, bc0, bc0, bc0};
            f32x4 a1 = {bc1, bc1, bc1, bc1};
            #pragma unroll
            for (int ks = 0; ks < 2; ++ks) {
                a0 = MFMA(xfrag[e][t][ks], wfrag[ks][0], a0);
                a1 = MFMA(xfrag[e][t][ks], wfrag[ks][1], a1);
            }
            #pragma unroll
            for (int r = 0; r < 4; ++r) {
                int row = rowA + q * 4 + r;   // C/D: row = quad*4 + reg
                unsigned pk = cvt2(fmaxf(a0[r], 0.f), fmaxf(a1[r], 0.f));
                ecs[row * EC_STRIDE + l15]      = (unsigned short)pk;
                ecs[row * EC_STRIDE + 16 + l15] = (unsigned short)(pk >> 16);
            }
        }
        #pragma unroll
        for (int t = 0; t < 4; ++t)
            ecfrag[e][t] = *reinterpret_cast<const bf16x8*>(
                &ecs[(w * 64 + t * 16 + l15) * EC_STRIDE + q * 8]);
    }

    // ---- hoist ALL per-g weights into registers (L2; issued here so their
    // ~300cy latency overlaps the tail of the enc MFMAs; first use at g=0).
    // 24 bf16x8 + 8 floats = 104 VGPR. Compile-time indexed (full unroll).
    bf16x8 wf0g[8], wf1g[8], wagg[8];
    float  bfl8[8];
    #pragma unroll
    for (int g = 0; g < 8; ++g) {
        const int r0 = g * 16 + l15;
        wf0g[g] = *reinterpret_cast<const bf16x8*>(&ws[WS_WF + r0 * XS_STRIDE + q * 8]);
        wf1g[g] = *reinterpret_cast<const bf16x8*>(&ws[WS_WF + r0 * XS_STRIDE + 32 + q * 8]);
        wagg[g] = *reinterpret_cast<const bf16x8*>(&ws[WS_WA + r0 * WA_STRIDE + q * 8]);
        bfl8[g] = bfv[r0];
    }

    // ---- fused g-loop, both elements interleaved, ZERO loads inside:
    // enc_feature + logits + unnormalized softmax agg. No max-subtraction
    // (logits O(+-3); exp2 safe). Fully unrolled -> frag arrays stay in
    // registers (rule: runtime-indexed ext_vector arrays spill to scratch).
    #pragma unroll
    for (int g = 0; g < 8; ++g) {
        const float bfl = bfl8[g];
        float num0 = 0.f, den0 = 0.f, num1 = 0.f, den1 = 0.f;
        #pragma unroll
        for (int t = 0; t < 4; ++t) {
            // element 0
            f32x4 za = {bfl, bfl, bfl, bfl};
            za = MFMA(xfrag[0][t][0], wf0g[g], za);
            f32x4 efa = MFMA(xfrag[0][t][1], wf1g[g], za);
            f32x4 zz0 = {0.f, 0.f, 0.f, 0.f};
            f32x4 lga = MFMA(ecfrag[0][t], wagg[g], zz0);
            // element 1 (independent chain)
            f32x4 zb = {bfl, bfl, bfl, bfl};
            zb = MFMA(xfrag[1][t][0], wf0g[g], zb);
            f32x4 efb = MFMA(xfrag[1][t][1], wf1g[g], zb);
            f32x4 zz1 = {0.f, 0.f, 0.f, 0.f};
            f32x4 lgb = MFMA(ecfrag[1][t], wagg[g], zz1);
            #pragma unroll
            for (int r = 0; r < 4; ++r) {
                float ea = fmaxf(efa[r], 0.f);
                float pa = fexp2(lga[r]);   // Wa pre-scaled by log2e in prep
                num0 = fmaf(pa, ea, num0);
                den0 += pa;
                float eb = fmaxf(efb[r], 0.f);
                float pb = fexp2(lgb[r]);
                num1 = fmaf(pb, eb, num1);
                den1 += pb;
            }
        }
        num0 += __shfl_xor(num0, 16, 64); num0 += __shfl_xor(num0, 32, 64);
        den0 += __shfl_xor(den0, 16, 64); den0 += __shfl_xor(den0, 32, 64);
        num1 += __shfl_xor(num1, 16, 64); num1 += __shfl_xor(num1, 32, 64);
        den1 += __shfl_xor(den1, 16, 64); den1 += __shfl_xor(den1, 32, 64);
        if (lane < 16) {
            aggnum[0][w][g * 16 + lane] = num0;
            aggden[0][w][g * 16 + lane] = den0;
            aggnum[1][w][g * 16 + lane] = num1;
            aggden[1][w][g * 16 + lane] = den1;
        }
    }
    __syncthreads();

    // ---- combine wave partials (both halves of the block active) ----
    {
        int e = tid >> 7, c = tid & 127;
        float num = aggnum[e][0][c] + aggnum[e][1][c] + aggnum[e][2][c] + aggnum[e][3][c];
        float den = aggden[e][0][c] + aggden[e][1][c] + aggden[e][2][c] + aggden[e][3][c];
        aggfull[e][c] = num / den;
    }
    __syncthreads();

    // ---- out = relu(agg @ Wl + bl): wl loaded ONCE, used for both elems ----
    {
        int c = tid & 127, h = tid >> 7;
        float acc0 = 0.f, acc1 = 0.f;
        #pragma unroll 16
        for (int k = h * 64; k < h * 64 + 64; ++k) {
            float wv = wl[k * LATD + c];
            acc0 = fmaf(aggfull[0][k], wv, acc0);
            acc1 = fmaf(aggfull[1][k], wv, acc1);
        }
        wlpart[h][0][c] = acc0;
        wlpart[h][1][c] = acc1;
    }
    __syncthreads();
    {
        int e = tid >> 7, c = tid & 127;
        out[(size_t)(e ? b1 : b0) * LATD + c] =
            fmaxf(wlpart[0][e][c] + wlpart[1][e][c] + blv[c], 0.f);
    }
}

extern "C" void kernel_launch(void* const* d_in, const int* in_sizes, int n_in,
                              void* d_out, int out_size, void* d_ws, size_t ws_size,
                              hipStream_t stream)
{
    const float* xg  = (const float*)d_in[1];
    const float* wc  = (const float*)d_in[2];
    const float* bc_ = (const float*)d_in[3];
    const float* wf  = (const float*)d_in[4];
    const float* bf_ = (const float*)d_in[5];
    const float* wa  = (const float*)d_in[6];
    const float* wl  = (const float*)d_in[8];
    const float* bl_ = (const float*)d_in[9];
    unsigned short* wsp = (unsigned short*)d_ws;   // needs 33,280 B of ws
    float* out = (float*)d_out;

    prep_kernel<<<8, 256, 0, stream>>>(wc, wf, wa, wsp);
    arm_main<<<512, 256, 0, stream>>>(xg, bc_, bf_, wl, bl_, wsp, out);
}